// Round 1
// baseline (786.966 us; speedup 1.0000x reference)
//
#include <hip/hip_runtime.h>
#include <hip/hip_bf16.h>
#include <cstdint>

#define H 1024
#define F 2048
#define E 8
#define T_TOK 4096
#define NPAIR (T_TOK * 2)   // top-2 per token
#define TMA 64              // max m-tiles per expert (4096/64)

typedef __attribute__((ext_vector_type(8))) short short8;
typedef __attribute__((ext_vector_type(4))) float f32x4;

__device__ __forceinline__ ushort f2bf(float f) {
  uint32_t u = __builtin_bit_cast(uint32_t, f);
  u += 0x7FFF + ((u >> 16) & 1);   // RNE
  return (ushort)(u >> 16);
}

// ---------------- router: fp32 logits, softmax, top-2, counts ----------------
__global__ __launch_bounds__(256) void router_kernel(
    const float* __restrict__ x, const float* __restrict__ gw,
    float* __restrict__ logits_out, int* __restrict__ sel,
    float* __restrict__ selw, int* __restrict__ counts) {
  int tid = threadIdx.x;
  int t = blockIdx.x * 4 + (tid >> 6);   // one wave per token
  int l = tid & 63;
  const float4* xr = (const float4*)(x + (size_t)t * H);
  const float4* g4 = (const float4*)gw;
  float acc[E];
#pragma unroll
  for (int e = 0; e < E; ++e) acc[e] = 0.f;
#pragma unroll
  for (int i = 0; i < 4; ++i) {
    float4 xv = xr[l + 64 * i];
#pragma unroll
    for (int e = 0; e < E; ++e) {
      float4 gv = g4[e * (H / 4) + l + 64 * i];
      acc[e] += xv.x * gv.x + xv.y * gv.y + xv.z * gv.z + xv.w * gv.w;
    }
  }
#pragma unroll
  for (int off = 32; off > 0; off >>= 1)
#pragma unroll
    for (int e = 0; e < E; ++e) acc[e] += __shfl_xor(acc[e], off, 64);

  if (l == 0) {
    float m = acc[0];
    for (int e = 1; e < E; ++e) m = fmaxf(m, acc[e]);
    float p[E], den = 0.f;
    for (int e = 0; e < E; ++e) { p[e] = __expf(acc[e] - m); den += p[e]; }
    float inv = 1.f / den;
    // top-2 of logits == top-2 of probs (softmax monotonic); ties -> lower idx
    int i0 = 0;
    for (int e = 1; e < E; ++e) if (acc[e] > acc[i0]) i0 = e;
    int i1 = (i0 == 0) ? 1 : 0;
    for (int e = 0; e < E; ++e) if (e != i0 && acc[e] > acc[i1]) i1 = e;
    for (int e = 0; e < E; ++e) logits_out[t * E + e] = acc[e];
    sel[t * 2] = i0; sel[t * 2 + 1] = i1;
    selw[t * 2] = p[i0] * inv; selw[t * 2 + 1] = p[i1] * inv;
    atomicAdd(&counts[i0], 1);
    atomicAdd(&counts[i1], 1);
  }
}

__global__ void offsets_kernel(const int* __restrict__ counts, int* __restrict__ offsets) {
  if (threadIdx.x == 0 && blockIdx.x == 0) {
    int s = 0;
    for (int e = 0; e < E; ++e) { offsets[e] = s; s += counts[e]; }
  }
}

__global__ __launch_bounds__(256) void bucket_kernel(
    const int* __restrict__ sel, const float* __restrict__ selw,
    const int* __restrict__ offsets, int* __restrict__ poscnt,
    int* __restrict__ pair_token, float* __restrict__ pair_weight) {
  int t = blockIdx.x * 256 + threadIdx.x;
  if (t >= T_TOK) return;
  for (int k = 0; k < 2; ++k) {
    int e = sel[t * 2 + k];
    int pos = atomicAdd(&poscnt[e], 1);
    int slot = offsets[e] + pos;
    pair_token[slot] = t;
    pair_weight[slot] = selw[t * 2 + k];
  }
}

// ---------------- dtype conversion ----------------
__global__ __launch_bounds__(256) void cast_x_kernel(const float* __restrict__ x,
                                                     ushort* __restrict__ xb) {
  int i = (blockIdx.x * 256 + threadIdx.x) * 4;
  float4 v = *(const float4*)(x + i);
  ushort4 o = make_ushort4(f2bf(v.x), f2bf(v.y), f2bf(v.z), f2bf(v.w));
  *(ushort4*)(xb + i) = o;
}

// src fp32 [e][R][C] -> dst bf16 [e][C][R]  (N-major so GEMM frags are K-contiguous)
__global__ __launch_bounds__(256) void transpose_cast_kernel(
    const float* __restrict__ src, ushort* __restrict__ dst, int R, int C) {
  __shared__ ushort tile[32][33];
  int e = blockIdx.z;
  src += (size_t)e * R * C;
  dst += (size_t)e * R * C;
  int c0 = blockIdx.x * 32, r0 = blockIdx.y * 32;
  int tx = threadIdx.x & 31, ty = threadIdx.x >> 5;
#pragma unroll
  for (int i = 0; i < 4; ++i)
    tile[ty + 8 * i][tx] = f2bf(src[(size_t)(r0 + ty + 8 * i) * C + c0 + tx]);
  __syncthreads();
#pragma unroll
  for (int i = 0; i < 4; ++i)
    dst[(size_t)(c0 + ty + 8 * i) * R + r0 + tx] = tile[tx][ty + 8 * i];
}

// ---------------- grouped GEMM A: h = silu(x@w1) * (x@w3) ----------------
// A: gathered x rows [cnt x H] bf16 (K-major), B: w1t/w3t [F x H] bf16 (K-major)
__global__ __launch_bounds__(256) void gemm_h_kernel(
    const ushort* __restrict__ xb, const ushort* __restrict__ w1t,
    const ushort* __restrict__ w3t, const int* __restrict__ pair_token,
    const int* __restrict__ counts, const int* __restrict__ offsets,
    ushort* __restrict__ hbuf) {
  int e = blockIdx.x / TMA;
  int mt = blockIdx.x % TMA;
  int cnt = counts[e];
  int m0 = mt * 64;
  if (m0 >= cnt) return;
  int base = offsets[e];
  int f0 = blockIdx.y * 64;

  __shared__ ushort lds[3 * 64 * 40];   // rows padded to 40 elems (80B, 16B-aligned)
  ushort* As = lds;
  ushort* B1s = lds + 64 * 40;
  ushort* B3s = lds + 2 * 64 * 40;

  int tid = threadIdx.x;
  int r = tid >> 2, c = tid & 3;        // staging: 4 x 16B chunks per 64B row
  int prow = base + m0 + r;
  if (prow > NPAIR - 1) prow = NPAIR - 1;
  int tok = pair_token[prow];
  const ushort* gA = xb + (size_t)tok * H + c * 8;
  const ushort* gB1 = w1t + ((size_t)e * F + f0 + r) * H + c * 8;
  const ushort* gB3 = w3t + ((size_t)e * F + f0 + r) * H + c * 8;
  int ldsoff = r * 40 + c * 8;

  int w = tid >> 6, l = tid & 63;
  int wm = w >> 1, wn = w & 1;
  int lr = l & 15, lk = (l >> 4) * 8;

  f32x4 c1[2][2], c3[2][2];
#pragma unroll
  for (int a = 0; a < 2; ++a)
#pragma unroll
    for (int b = 0; b < 2; ++b) { c1[a][b] = (f32x4)0.f; c3[a][b] = (f32x4)0.f; }

  for (int k0 = 0; k0 < H; k0 += 32) {
    __syncthreads();
    *(short8*)(As + ldsoff) = *(const short8*)(gA + k0);
    *(short8*)(B1s + ldsoff) = *(const short8*)(gB1 + k0);
    *(short8*)(B3s + ldsoff) = *(const short8*)(gB3 + k0);
    __syncthreads();
    short8 af[2], b1f[2], b3f[2];
#pragma unroll
    for (int ms = 0; ms < 2; ++ms)
      af[ms] = *(const short8*)(As + (wm * 32 + ms * 16 + lr) * 40 + lk);
#pragma unroll
    for (int ns = 0; ns < 2; ++ns) {
      b1f[ns] = *(const short8*)(B1s + (wn * 32 + ns * 16 + lr) * 40 + lk);
      b3f[ns] = *(const short8*)(B3s + (wn * 32 + ns * 16 + lr) * 40 + lk);
    }
#pragma unroll
    for (int ms = 0; ms < 2; ++ms)
#pragma unroll
      for (int ns = 0; ns < 2; ++ns) {
        c1[ms][ns] = __builtin_amdgcn_mfma_f32_16x16x32_bf16(af[ms], b1f[ns], c1[ms][ns], 0, 0, 0);
        c3[ms][ns] = __builtin_amdgcn_mfma_f32_16x16x32_bf16(af[ms], b3f[ns], c3[ms][ns], 0, 0, 0);
      }
  }
#pragma unroll
  for (int ms = 0; ms < 2; ++ms)
#pragma unroll
    for (int ns = 0; ns < 2; ++ns)
#pragma unroll
      for (int rg = 0; rg < 4; ++rg) {
        int ml = wm * 32 + ms * 16 + (l >> 4) * 4 + rg;   // C/D: row=(lane>>4)*4+reg
        if (m0 + ml < cnt) {
          int nl = wn * 32 + ns * 16 + (l & 15);          // col=lane&15
          float g = c1[ms][ns][rg], u = c3[ms][ns][rg];
          float hv = g / (1.f + __expf(-g)) * u;          // silu(g)*u
          hbuf[(size_t)(base + m0 + ml) * F + f0 + nl] = f2bf(hv);
        }
      }
}

// ---------------- grouped GEMM B: y += weight * (h @ w2) ----------------
__global__ __launch_bounds__(256) void gemm_out_kernel(
    const ushort* __restrict__ hbuf, const ushort* __restrict__ w2t,
    const int* __restrict__ pair_token, const float* __restrict__ pair_weight,
    const int* __restrict__ counts, const int* __restrict__ offsets,
    float* __restrict__ y) {
  int e = blockIdx.x / TMA;
  int mt = blockIdx.x % TMA;
  int cnt = counts[e];
  int m0 = mt * 64;
  if (m0 >= cnt) return;
  int base = offsets[e];
  int n0 = blockIdx.y * 64;

  __shared__ ushort lds[2 * 64 * 40];
  ushort* As = lds;
  ushort* Bs = lds + 64 * 40;
  __shared__ int tok_s[64];
  __shared__ float wt_s[64];

  int tid = threadIdx.x;
  if (tid < 64) {
    int p = base + m0 + tid;
    if (p > NPAIR - 1) p = NPAIR - 1;
    tok_s[tid] = pair_token[p];
    wt_s[tid] = pair_weight[p];
  }

  int r = tid >> 2, c = tid & 3;
  const ushort* gA = hbuf + (size_t)(base + m0 + r) * F + c * 8;  // h rows contiguous per expert
  const ushort* gB = w2t + ((size_t)e * H + n0 + r) * F + c * 8;
  int ldsoff = r * 40 + c * 8;

  int w = tid >> 6, l = tid & 63;
  int wm = w >> 1, wn = w & 1;
  int lr = l & 15, lk = (l >> 4) * 8;

  f32x4 cc[2][2];
#pragma unroll
  for (int a = 0; a < 2; ++a)
#pragma unroll
    for (int b = 0; b < 2; ++b) cc[a][b] = (f32x4)0.f;

  for (int k0 = 0; k0 < F; k0 += 32) {
    __syncthreads();
    *(short8*)(As + ldsoff) = *(const short8*)(gA + k0);
    *(short8*)(Bs + ldsoff) = *(const short8*)(gB + k0);
    __syncthreads();
    short8 af[2], bf_[2];
#pragma unroll
    for (int ms = 0; ms < 2; ++ms)
      af[ms] = *(const short8*)(As + (wm * 32 + ms * 16 + lr) * 40 + lk);
#pragma unroll
    for (int ns = 0; ns < 2; ++ns)
      bf_[ns] = *(const short8*)(Bs + (wn * 32 + ns * 16 + lr) * 40 + lk);
#pragma unroll
    for (int ms = 0; ms < 2; ++ms)
#pragma unroll
      for (int ns = 0; ns < 2; ++ns)
        cc[ms][ns] = __builtin_amdgcn_mfma_f32_16x16x32_bf16(af[ms], bf_[ns], cc[ms][ns], 0, 0, 0);
  }
#pragma unroll
  for (int ms = 0; ms < 2; ++ms)
#pragma unroll
    for (int ns = 0; ns < 2; ++ns)
#pragma unroll
      for (int rg = 0; rg < 4; ++rg) {
        int ml = wm * 32 + ms * 16 + (l >> 4) * 4 + rg;
        if (m0 + ml < cnt) {
          int nl = wn * 32 + ns * 16 + (l & 15);
          atomicAdd(&y[(size_t)tok_s[ml] * H + n0 + nl], cc[ms][ns][rg] * wt_s[ml]);
        }
      }
}

extern "C" void kernel_launch(void* const* d_in, const int* in_sizes, int n_in,
                              void* d_out, int out_size, void* d_ws, size_t ws_size,
                              hipStream_t stream) {
  const float* x  = (const float*)d_in[0];
  const float* gw = (const float*)d_in[1];
  const float* w1 = (const float*)d_in[2];
  const float* w3 = (const float*)d_in[3];
  const float* w2 = (const float*)d_in[4];
  float* y = (float*)d_out;                       // [T, H] fp32
  float* logits_out = y + (size_t)T_TOK * H;      // [T, E] fp32 (output #2)

  char* ws = (char*)d_ws;
  size_t off = 0;
  auto alloc = [&](size_t bytes) {
    char* p = ws + off;
    off += (bytes + 255) & ~size_t(255);
    return p;
  };
  ushort* xb   = (ushort*)alloc((size_t)T_TOK * H * 2);
  ushort* w1t  = (ushort*)alloc((size_t)E * F * H * 2);
  ushort* w3t  = (ushort*)alloc((size_t)E * F * H * 2);
  ushort* w2t  = (ushort*)alloc((size_t)E * H * F * 2);
  ushort* hbuf = (ushort*)alloc((size_t)(NPAIR + 64) * F * 2);  // +64 rows tile padding
  int*   pair_token  = (int*)alloc(NPAIR * 4);
  float* pair_weight = (float*)alloc(NPAIR * 4);
  int*   sel   = (int*)alloc(T_TOK * 2 * 4);
  float* selw  = (float*)alloc(T_TOK * 2 * 4);
  int* counts  = (int*)alloc(E * 4);
  int* offsets = (int*)alloc(E * 4);
  int* poscnt  = (int*)alloc(E * 4);

  hipMemsetAsync(y, 0, (size_t)T_TOK * H * 4, stream);   // d_out poisoned each call
  hipMemsetAsync(counts, 0, E * 4, stream);
  hipMemsetAsync(poscnt, 0, E * 4, stream);

  router_kernel<<<T_TOK / 4, 256, 0, stream>>>(x, gw, logits_out, sel, selw, counts);
  offsets_kernel<<<1, 64, 0, stream>>>(counts, offsets);
  bucket_kernel<<<T_TOK / 256, 256, 0, stream>>>(sel, selw, offsets, poscnt,
                                                 pair_token, pair_weight);
  cast_x_kernel<<<(T_TOK * H / 4) / 256, 256, 0, stream>>>(x, xb);
  transpose_cast_kernel<<<dim3(F / 32, H / 32, E), 256, 0, stream>>>(w1, w1t, H, F);
  transpose_cast_kernel<<<dim3(F / 32, H / 32, E), 256, 0, stream>>>(w3, w3t, H, F);
  transpose_cast_kernel<<<dim3(H / 32, F / 32, E), 256, 0, stream>>>(w2, w2t, F, H);
  gemm_h_kernel<<<dim3(E * TMA, F / 64), 256, 0, stream>>>(xb, w1t, w3t, pair_token,
                                                           counts, offsets, hbuf);
  gemm_out_kernel<<<dim3(E * TMA, H / 64), 256, 0, stream>>>(hbuf, w2t, pair_token,
                                                             pair_weight, counts,
                                                             offsets, y);
}